// Round 1
// baseline (879.940 us; speedup 1.0000x reference)
//
#include <hip/hip_runtime.h>
#include <cstdint>

#define NUM_CLASSES 81
#define BB 32
#define PP 32768

__device__ __forceinline__ unsigned f2key(float f) {
    unsigned u = __float_as_uint(f);
    return u ^ (unsigned)(((int)u >> 31) | (int)0x80000000u);
}
__device__ __forceinline__ float key2f(unsigned k) {
    unsigned u = (k & 0x80000000u) ? (k ^ 0x80000000u) : ~k;
    return __uint_as_float(u);
}

__global__ void mbl_init_kernel(float* __restrict__ acc, int* __restrict__ num_pos) {
    int t = threadIdx.x;
    if (t < 4) acc[t] = 0.f;
    if (t < BB) num_pos[t] = 0;
}

// One thread per anchor: online logsumexp over 81 classes, smooth-L1 for
// positives, write mining score loss_c, reduce scalars per block -> atomics.
__global__ __launch_bounds__(256) void mbl_main_kernel(
    const float* __restrict__ loc_t, const float* __restrict__ loc_data,
    const int* __restrict__ conf_t, const float* __restrict__ conf,
    float* __restrict__ loss_c, float* __restrict__ acc, int* __restrict__ num_pos)
{
    const int t = threadIdx.x;
    const int idx = blockIdx.x * 256 + t;
    const int b = idx >> 15;  // idx / PP

    const int label = conf_t[idx];
    const bool pos = label > 0;
    const bool regard = label == -1;
    const int lab = label < 0 ? 0 : label;

    const float* cp = conf + (size_t)idx * NUM_CLASSES;
    float m = -3.0e38f, s = 0.f, g = 0.f;
    #pragma unroll 3
    for (int j = 0; j < NUM_CLASSES; ++j) {
        float x = cp[j];
        if (j == lab) g = x;
        float mn = fmaxf(m, x);
        s = s * __expf(m - mn) + __expf(x - mn);
        m = mn;
    }
    const float ce = __logf(s) + m - g;

    loss_c[idx] = (pos || regard) ? 0.f : ce;

    float ll = 0.f;
    if (pos) {
        const float* lt = loc_t + (size_t)idx * 4;
        const float* ld = loc_data + (size_t)idx * 4;
        #pragma unroll
        for (int j = 0; j < 4; ++j) {
            float d = fabsf(ld[j] - lt[j]);
            ll += (d < 1.f) ? 0.5f * d * d : d - 0.5f;
        }
    }
    const float pce = pos ? ce : 0.f;
    const float pcnt = pos ? 1.f : 0.f;

    __shared__ float r0[256];
    __shared__ float r1[256];
    __shared__ float r2[256];
    r0[t] = ll; r1[t] = pce; r2[t] = pcnt;
    __syncthreads();
    #pragma unroll
    for (int off = 128; off > 0; off >>= 1) {
        if (t < off) { r0[t] += r0[t + off]; r1[t] += r1[t + off]; r2[t] += r2[t + off]; }
        __syncthreads();
    }
    if (t == 0) {
        atomicAdd(&acc[0], r0[0]);
        atomicAdd(&acc[1], r1[0]);
        atomicAdd(&num_pos[b], (int)r2[0]);
    }
}

// One block per batch row: radix-select k-th largest loss_c (k = min(3*num_pos, P-1)),
// then sum of top-k -> acc[2].
__global__ __launch_bounds__(1024) void mbl_select_kernel(
    const float* __restrict__ loss_c, const int* __restrict__ num_pos,
    float* __restrict__ acc)
{
    const int b = blockIdx.x;
    const int t = threadIdx.x;
    const float* row = loss_c + (size_t)b * PP;

    int k = 3 * num_pos[b];
    if (k > PP - 1) k = PP - 1;
    if (k <= 0) return;  // uniform across block: num_pos[b] is the same for all threads

    __shared__ unsigned hist[256];
    __shared__ unsigned sh_prefix;
    __shared__ unsigned sh_remaining;
    __shared__ float red[1024];

    if (t == 0) { sh_prefix = 0u; sh_remaining = (unsigned)k; }
    __syncthreads();

    unsigned prefmask = 0u;
    for (int shift = 24; shift >= 0; shift -= 8) {
        if (t < 256) hist[t] = 0u;
        __syncthreads();
        const unsigned prefix = sh_prefix;
        for (int e = t; e < PP; e += 1024) {
            unsigned key = f2key(row[e]);
            if ((key & prefmask) == prefix)
                atomicAdd(&hist[(key >> shift) & 255u], 1u);
        }
        __syncthreads();
        if (t == 0) {
            unsigned rem = sh_remaining;
            int d = 255;
            for (; d > 0; --d) {
                unsigned c = hist[d];
                if (rem <= c) break;
                rem -= c;
            }
            sh_prefix = prefix | ((unsigned)d << shift);
            sh_remaining = rem;
        }
        __syncthreads();
        prefmask |= 0xFFu << shift;
    }

    const unsigned T = sh_prefix;      // key of the k-th largest element
    const unsigned rem = sh_remaining; // how many elements == T to include

    float partial = 0.f;
    for (int e = t; e < PP; e += 1024) {
        float v = row[e];
        if (f2key(v) > T) partial += v;
    }
    red[t] = partial;
    __syncthreads();
    #pragma unroll
    for (int off = 512; off > 0; off >>= 1) {
        if (t < off) red[t] += red[t + off];
        __syncthreads();
    }
    if (t == 0) atomicAdd(&acc[2], red[0] + (float)rem * key2f(T));
}

__global__ void mbl_final_kernel(const float* __restrict__ acc,
                                 const int* __restrict__ num_pos,
                                 float* __restrict__ out)
{
    if (threadIdx.x == 0 && blockIdx.x == 0) {
        int n = 0;
        for (int i = 0; i < BB; ++i) n += num_pos[i];
        const float N = (float)n;
        out[0] = acc[0] / N;
        out[1] = (acc[1] + acc[2]) / N;
    }
}

extern "C" void kernel_launch(void* const* d_in, const int* in_sizes, int n_in,
                              void* d_out, int out_size, void* d_ws, size_t ws_size,
                              hipStream_t stream) {
    const float* loc_t    = (const float*)d_in[0];
    const float* loc_data = (const float*)d_in[1];
    const int*   conf_t   = (const int*)d_in[2];
    const float* conf     = (const float*)d_in[3];
    float* out = (float*)d_out;

    // workspace layout: [B*P floats loss_c][256B pad: acc(4 floats)][num_pos(B ints)]
    char* ws = (char*)d_ws;
    float* loss_c  = (float*)ws;
    float* acc     = (float*)(ws + (size_t)BB * PP * sizeof(float));
    int*   num_pos = (int*)(ws + (size_t)BB * PP * sizeof(float) + 256);

    mbl_init_kernel<<<1, 64, 0, stream>>>(acc, num_pos);
    mbl_main_kernel<<<(BB * PP) / 256, 256, 0, stream>>>(
        loc_t, loc_data, conf_t, conf, loss_c, acc, num_pos);
    mbl_select_kernel<<<BB, 1024, 0, stream>>>(loss_c, num_pos, acc);
    mbl_final_kernel<<<1, 64, 0, stream>>>(acc, num_pos, out);
}

// Round 2
// 696.956 us; speedup vs baseline: 1.2625x; 1.2625x over previous
//
#include <hip/hip_runtime.h>
#include <cstdint>

#define NUM_CLASSES 81
#define BB 32
#define PP 32768
#define TPB 128   // threads per block (main)
#define APB 128   // anchors per block (main)

__device__ __forceinline__ unsigned f2key(float f) {
    unsigned u = __float_as_uint(f);
    return u ^ (unsigned)(((int)u >> 31) | (int)0x80000000u);
}
__device__ __forceinline__ float key2f(unsigned k) {
    unsigned u = (k & 0x80000000u) ? (k ^ 0x80000000u) : ~k;
    return __uint_as_float(u);
}

__global__ void mbl_init_kernel(float* __restrict__ acc, int* __restrict__ num_pos) {
    int t = threadIdx.x;
    if (t < 4) acc[t] = 0.f;
    if (t < BB) num_pos[t] = 0;
}

// 128 threads / 128 anchors per block. Stage conf tile into LDS with coalesced
// float4 loads, then per-thread 2-pass LSE from LDS (stride 81 = odd -> 2
// lanes/bank, conflict-free). loc read only on positive lanes.
__global__ __launch_bounds__(TPB) void mbl_main_kernel(
    const float* __restrict__ loc_t, const float* __restrict__ loc_data,
    const int* __restrict__ conf_t, const float* __restrict__ conf,
    float* __restrict__ loss_c, float* __restrict__ acc, int* __restrict__ num_pos)
{
    __shared__ __align__(16) float tile[APB * NUM_CLASSES];  // 41472 B
    const int t = threadIdx.x;
    const int base = blockIdx.x * APB;

    // stage: APB*81 floats = 2592 float4s, contiguous & 16B-aligned
    const float4* s4 = (const float4*)(conf + (size_t)base * NUM_CLASSES);
    float4* l4 = (float4*)tile;
    for (int i = t; i < (APB * NUM_CLASSES) / 4; i += TPB) l4[i] = s4[i];
    __syncthreads();

    const int idx = base + t;
    const int label = conf_t[idx];
    const bool pos = label > 0;
    const bool regard = label == -1;
    const int lab = label < 0 ? 0 : label;

    const float* cp = tile + t * NUM_CLASSES;
    float m = cp[0];
    #pragma unroll 9
    for (int j = 1; j < NUM_CLASSES; ++j) m = fmaxf(m, cp[j]);
    float s = 0.f;
    #pragma unroll 9
    for (int j = 0; j < NUM_CLASSES; ++j) s += __expf(cp[j] - m);
    const float g = cp[lab];
    const float ce = __logf(s) + m - g;

    loss_c[idx] = (pos || regard) ? 0.f : ce;

    float ll = 0.f;
    if (pos) {
        float4 a = ((const float4*)loc_data)[idx];
        float4 b4 = ((const float4*)loc_t)[idx];
        float d0 = fabsf(a.x - b4.x), d1 = fabsf(a.y - b4.y);
        float d2 = fabsf(a.z - b4.z), d3 = fabsf(a.w - b4.w);
        ll  = (d0 < 1.f) ? 0.5f * d0 * d0 : d0 - 0.5f;
        ll += (d1 < 1.f) ? 0.5f * d1 * d1 : d1 - 0.5f;
        ll += (d2 < 1.f) ? 0.5f * d2 * d2 : d2 - 0.5f;
        ll += (d3 < 1.f) ? 0.5f * d3 * d3 : d3 - 0.5f;
    }
    float pce = pos ? ce : 0.f;
    float pcnt = pos ? 1.f : 0.f;

    #pragma unroll
    for (int off = 32; off > 0; off >>= 1) {
        ll   += __shfl_down(ll, off);
        pce  += __shfl_down(pce, off);
        pcnt += __shfl_down(pcnt, off);
    }
    __shared__ float wsum[3][TPB / 64];
    const int w = t >> 6;
    if ((t & 63) == 0) { wsum[0][w] = ll; wsum[1][w] = pce; wsum[2][w] = pcnt; }
    __syncthreads();
    if (t == 0) {
        float s0 = 0.f, s1 = 0.f, s2 = 0.f;
        #pragma unroll
        for (int i = 0; i < TPB / 64; ++i) { s0 += wsum[0][i]; s1 += wsum[1][i]; s2 += wsum[2][i]; }
        atomicAdd(&acc[0], s0);
        atomicAdd(&acc[1], s1);
        atomicAdd(&num_pos[base >> 15], (int)s2);
    }
}

// One block per batch row: radix-select k-th largest loss_c, sum top-k.
// Wave-aggregated histogram atomics (ballot peer-matching) + parallel
// suffix-scan digit selection.
__global__ __launch_bounds__(1024) void mbl_select_kernel(
    const float* __restrict__ loss_c, const int* __restrict__ num_pos,
    float* __restrict__ acc)
{
    const int b = blockIdx.x;
    const int t = threadIdx.x;
    const int lane = t & 63;
    const float* row = loss_c + (size_t)b * PP;

    int k = 3 * num_pos[b];
    if (k > PP - 1) k = PP - 1;
    if (k <= 0) return;  // uniform across block

    __shared__ unsigned hist[256];
    __shared__ unsigned suf[256];
    __shared__ unsigned sh_prefix;
    __shared__ unsigned sh_remaining;
    __shared__ float red[1024];

    if (t == 0) { sh_prefix = 0u; sh_remaining = (unsigned)k; }
    __syncthreads();

    unsigned prefmask = 0u;
    for (int shift = 24; shift >= 0; shift -= 8) {
        if (t < 256) hist[t] = 0u;
        __syncthreads();
        const unsigned prefix = sh_prefix;
        const unsigned krem = sh_remaining;

        for (int e = t; e < PP; e += 1024) {
            unsigned key = f2key(row[e]);
            bool match = (key & prefmask) == prefix;
            if (match) {
                unsigned d = (key >> shift) & 255u;
                unsigned long long peers = __ballot(1);  // active (matching) lanes
                #pragma unroll
                for (int bit = 0; bit < 8; ++bit) {
                    unsigned long long bm = __ballot((d >> bit) & 1u);
                    peers &= ((d >> bit) & 1u) ? bm : ~bm;
                }
                if ((__ffsll((unsigned long long)peers) - 1) == lane)
                    atomicAdd(&hist[d], (unsigned)__popcll(peers));
            }
        }
        __syncthreads();

        // inclusive suffix scan of hist -> suf  (suf[d] = sum_{j>=d} hist[j])
        if (t < 256) suf[t] = hist[t];
        __syncthreads();
        #pragma unroll
        for (int step = 1; step < 256; step <<= 1) {
            unsigned v = 0u;
            if (t < 256) v = suf[t] + ((t + step < 256) ? suf[t + step] : 0u);
            __syncthreads();
            if (t < 256) suf[t] = v;
            __syncthreads();
        }
        // pick digit d*: largest d with suf[d] >= krem
        if (t < 256) {
            unsigned above = (t == 255) ? 0u : suf[t + 1];
            if (suf[t] >= krem && above < krem) {
                sh_prefix = prefix | ((unsigned)t << shift);
                sh_remaining = krem - above;
            }
        }
        __syncthreads();
        prefmask |= 0xFFu << shift;
    }

    const unsigned T = sh_prefix;      // key of the k-th largest element
    const unsigned rem = sh_remaining; // count of elements == T to include

    float partial = 0.f;
    for (int e = t; e < PP; e += 1024) {
        float v = row[e];
        if (f2key(v) > T) partial += v;
    }
    red[t] = partial;
    __syncthreads();
    #pragma unroll
    for (int off = 512; off > 0; off >>= 1) {
        if (t < off) red[t] += red[t + off];
        __syncthreads();
    }
    if (t == 0) atomicAdd(&acc[2], red[0] + (float)rem * key2f(T));
}

__global__ void mbl_final_kernel(const float* __restrict__ acc,
                                 const int* __restrict__ num_pos,
                                 float* __restrict__ out)
{
    if (threadIdx.x == 0 && blockIdx.x == 0) {
        int n = 0;
        for (int i = 0; i < BB; ++i) n += num_pos[i];
        const float N = (float)n;
        out[0] = acc[0] / N;
        out[1] = (acc[1] + acc[2]) / N;
    }
}

extern "C" void kernel_launch(void* const* d_in, const int* in_sizes, int n_in,
                              void* d_out, int out_size, void* d_ws, size_t ws_size,
                              hipStream_t stream) {
    const float* loc_t    = (const float*)d_in[0];
    const float* loc_data = (const float*)d_in[1];
    const int*   conf_t   = (const int*)d_in[2];
    const float* conf     = (const float*)d_in[3];
    float* out = (float*)d_out;

    // workspace: [B*P floats loss_c][256B pad: acc(4 floats)][num_pos(B ints)]
    char* ws = (char*)d_ws;
    float* loss_c  = (float*)ws;
    float* acc     = (float*)(ws + (size_t)BB * PP * sizeof(float));
    int*   num_pos = (int*)(ws + (size_t)BB * PP * sizeof(float) + 256);

    mbl_init_kernel<<<1, 64, 0, stream>>>(acc, num_pos);
    mbl_main_kernel<<<(BB * PP) / APB, TPB, 0, stream>>>(
        loc_t, loc_data, conf_t, conf, loss_c, acc, num_pos);
    mbl_select_kernel<<<BB, 1024, 0, stream>>>(loss_c, num_pos, acc);
    mbl_final_kernel<<<1, 64, 0, stream>>>(acc, num_pos, out);
}

// Round 3
// 512.948 us; speedup vs baseline: 1.7155x; 1.3587x over previous
//
#include <hip/hip_runtime.h>
#include <cstdint>

#define NUM_CLASSES 81
#define BB 32
#define PP 32768
#define CA 64                               // anchors per chunk
#define TPB 256
#define CHUNK_FLOATS (CA * NUM_CLASSES)     // 5184
#define CHUNK_F4 (CHUNK_FLOATS / 4)         // 1296
#define NCHUNK (BB * PP / CA)               // 16384
#define GRID_MAIN 768
#define NP_STRIDE 32                        // num_pos padded: 1 counter per 128 B

__device__ __forceinline__ unsigned f2key(float f) {
    unsigned u = __float_as_uint(f);
    return u ^ (unsigned)(((int)u >> 31) | (int)0x80000000u);
}
__device__ __forceinline__ float key2f(unsigned k) {
    unsigned u = (k & 0x80000000u) ? (k ^ 0x80000000u) : ~k;
    return __uint_as_float(u);
}

// ---- workspace layout (after the 4 MB loss_c array) ----
// off0+0    : acc[4]  (float)   acc0=loss_l, acc1=pos ce, acc2=neg ce
// off0+256  : num_pos[32*NP_STRIDE] (int, stride 32 ints = 128 B)
// off0+4608 : prefix[32]    (unsigned)
// off0+4864 : remaining[32] (unsigned)
// off0+5120 : ghist[32*256] (unsigned)
// zero words = (5120 + 32768)/4 = 9472 = 37*256

__global__ void mbl_zero_kernel(unsigned* __restrict__ p, int n) {
    int i = blockIdx.x * 256 + threadIdx.x;
    if (i < n) p[i] = 0u;
}

__global__ __launch_bounds__(TPB, 4) void mbl_main_kernel(
    const float* __restrict__ loc_t, const float* __restrict__ loc_data,
    const int* __restrict__ conf_t, const float* __restrict__ conf,
    float* __restrict__ loss_c, float* __restrict__ acc, int* __restrict__ num_pos)
{
    __shared__ __align__(16) float tile[2][CHUNK_FLOATS];   // 41472 B
    __shared__ float wred[2][TPB / 64];

    const int t = threadIdx.x;
    const int lane = t & 63;
    const int w = t >> 6;
    const int q = lane >> 4;                 // quarter 0..3
    const int a_loc = (w << 4) | (lane & 15); // anchor-in-chunk 0..63

    float sum_ll = 0.f, sum_pce = 0.f;

    int c = blockIdx.x;
    {   // prologue stage into buffer 0
        const float4* src = (const float4*)(conf + (size_t)c * CHUNK_FLOATS);
        float4* dst = (float4*)tile[0];
        #pragma unroll
        for (int i = 0; i < 5; ++i) dst[t + i * TPB] = src[t + i * TPB];
        if (t < CHUNK_F4 - 5 * TPB) dst[t + 5 * TPB] = src[t + 5 * TPB];
    }
    int parity = 0;
    const int stride = gridDim.x;
    for (; c < NCHUNK; c += stride) {
        __syncthreads();  // staged buffer[parity] ready; prior compute done
        const int nc = c + stride;
        if (nc < NCHUNK) {   // stage next chunk into the other buffer
            const float4* src = (const float4*)(conf + (size_t)nc * CHUNK_FLOATS);
            float4* dst = (float4*)tile[parity ^ 1];
            #pragma unroll
            for (int i = 0; i < 5; ++i) dst[t + i * TPB] = src[t + i * TPB];
            if (t < CHUNK_F4 - 5 * TPB) dst[t + 5 * TPB] = src[t + 5 * TPB];
        }
        // ---- compute chunk c from tile[parity] ----
        const float* cp = tile[parity] + a_loc * NUM_CLASSES + q * 20;
        float s = 0.f;
        #pragma unroll
        for (int j = 0; j < 20; ++j) s += __expf(cp[j]);
        if (q == 3) s += __expf(cp[20]);
        s += __shfl_xor(s, 16);
        s += __shfl_xor(s, 32);              // all 4 quarters combined

        bool posl = false;
        if (q == 0) {
            const int idx = c * CA + a_loc;
            const int label = conf_t[idx];
            posl = label > 0;
            const bool regard = label == -1;
            const int lab = label < 0 ? 0 : label;
            const float g = tile[parity][a_loc * NUM_CLASSES + lab];
            const float ce = __logf(s) - g;
            loss_c[idx] = (posl || regard) ? 0.f : ce;
            if (posl) {
                float4 a4 = ((const float4*)loc_data)[idx];
                float4 b4 = ((const float4*)loc_t)[idx];
                float d0 = fabsf(a4.x - b4.x), d1 = fabsf(a4.y - b4.y);
                float d2 = fabsf(a4.z - b4.z), d3 = fabsf(a4.w - b4.w);
                sum_ll += (d0 < 1.f) ? 0.5f * d0 * d0 : d0 - 0.5f;
                sum_ll += (d1 < 1.f) ? 0.5f * d1 * d1 : d1 - 0.5f;
                sum_ll += (d2 < 1.f) ? 0.5f * d2 * d2 : d2 - 0.5f;
                sum_ll += (d3 < 1.f) ? 0.5f * d3 * d3 : d3 - 0.5f;
                sum_pce += ce;
            }
        }
        unsigned long long bal = __ballot(posl);
        if (lane == 0 && bal)
            atomicAdd(&num_pos[(c >> 9) * NP_STRIDE], (int)__popcll(bal));
        parity ^= 1;
    }
    // reduce scalars
    #pragma unroll
    for (int off = 32; off > 0; off >>= 1) {
        sum_ll += __shfl_down(sum_ll, off);
        sum_pce += __shfl_down(sum_pce, off);
    }
    if (lane == 0) { wred[0][w] = sum_ll; wred[1][w] = sum_pce; }
    __syncthreads();
    if (t == 0) {
        float s0 = 0.f, s1 = 0.f;
        #pragma unroll
        for (int i = 0; i < TPB / 64; ++i) { s0 += wred[0][i]; s1 += wred[1][i]; }
        atomicAdd(&acc[0], s0);
        atomicAdd(&acc[1], s1);
    }
}

// 512 blocks: 32 rows x 16 slices, 2048 elements each. LDS-private histogram.
__global__ __launch_bounds__(256) void mbl_hist_kernel(
    const float* __restrict__ loss_c, const unsigned* __restrict__ prefix,
    unsigned* __restrict__ ghist, int shift, unsigned mask)
{
    const int b = blockIdx.x >> 4;
    const int slice = blockIdx.x & 15;
    const int t = threadIdx.x;
    __shared__ unsigned h[256];
    h[t] = 0u;
    __syncthreads();
    const unsigned pref = prefix[b];
    const float4* r4 = (const float4*)(loss_c + (size_t)b * PP + slice * 2048);
    #pragma unroll
    for (int i = 0; i < 2; ++i) {
        float4 v = r4[t + 256 * i];
        unsigned k0 = f2key(v.x), k1 = f2key(v.y), k2 = f2key(v.z), k3 = f2key(v.w);
        if ((k0 & mask) == pref) atomicAdd(&h[(k0 >> shift) & 255u], 1u);
        if ((k1 & mask) == pref) atomicAdd(&h[(k1 >> shift) & 255u], 1u);
        if ((k2 & mask) == pref) atomicAdd(&h[(k2 >> shift) & 255u], 1u);
        if ((k3 & mask) == pref) atomicAdd(&h[(k3 >> shift) & 255u], 1u);
    }
    __syncthreads();
    unsigned cnt = h[t];
    if (cnt) atomicAdd(&ghist[b * 256 + t], cnt);
}

// 32 blocks: suffix-scan the 256-bin histogram, pick digit, clear hist.
__global__ __launch_bounds__(256) void mbl_pick_kernel(
    unsigned* __restrict__ ghist, unsigned* __restrict__ prefix,
    unsigned* __restrict__ remaining, const int* __restrict__ num_pos,
    int shift, int first)
{
    const int b = blockIdx.x;
    const int t = threadIdx.x;
    __shared__ unsigned suf[256];
    __shared__ unsigned sh_k;
    if (t == 0) {
        unsigned k;
        if (first) {
            int kk = 3 * num_pos[b * NP_STRIDE];
            if (kk > PP - 1) kk = PP - 1;
            if (kk <= 0) { prefix[b] = 0xFFFFFFFFu; remaining[b] = 0u; k = 0u; }
            else k = (unsigned)kk;
        } else {
            k = remaining[b];
        }
        sh_k = k;
    }
    __syncthreads();
    const unsigned krem = sh_k;
    if (krem == 0u) return;   // uniform across block

    unsigned hv = ghist[b * 256 + t];
    ghist[b * 256 + t] = 0u;  // clear for next pass
    suf[t] = hv;
    __syncthreads();
    #pragma unroll
    for (int step = 1; step < 256; step <<= 1) {
        unsigned v = suf[t] + ((t + step < 256) ? suf[t + step] : 0u);
        __syncthreads();
        suf[t] = v;
        __syncthreads();
    }
    const unsigned above = (t == 255) ? 0u : suf[t + 1];
    if (suf[t] >= krem && above < krem) {
        prefix[b] |= ((unsigned)t) << shift;
        remaining[b] = krem - above;
    }
}

// 512 blocks: sum values with key strictly greater than threshold T.
__global__ __launch_bounds__(256) void mbl_sum_kernel(
    const float* __restrict__ loss_c, const unsigned* __restrict__ prefix,
    float* __restrict__ acc)
{
    const int b = blockIdx.x >> 4;
    const int slice = blockIdx.x & 15;
    const int t = threadIdx.x;
    const int lane = t & 63;
    const int w = t >> 6;
    const unsigned T = prefix[b];
    const float4* r4 = (const float4*)(loss_c + (size_t)b * PP + slice * 2048);
    float partial = 0.f;
    #pragma unroll
    for (int i = 0; i < 2; ++i) {
        float4 v = r4[t + 256 * i];
        if (f2key(v.x) > T) partial += v.x;
        if (f2key(v.y) > T) partial += v.y;
        if (f2key(v.z) > T) partial += v.z;
        if (f2key(v.w) > T) partial += v.w;
    }
    #pragma unroll
    for (int off = 32; off > 0; off >>= 1) partial += __shfl_down(partial, off);
    __shared__ float r[4];
    if (lane == 0) r[w] = partial;
    __syncthreads();
    if (t == 0) atomicAdd(&acc[2], r[0] + r[1] + r[2] + r[3]);
}

__global__ void mbl_final_kernel(const float* __restrict__ acc,
                                 const int* __restrict__ num_pos,
                                 const unsigned* __restrict__ prefix,
                                 const unsigned* __restrict__ remaining,
                                 float* __restrict__ out)
{
    if (threadIdx.x == 0 && blockIdx.x == 0) {
        int n = 0;
        float extra = 0.f;
        for (int i = 0; i < BB; ++i) {
            n += num_pos[i * NP_STRIDE];
            unsigned rem = remaining[i];
            if (rem) extra += (float)rem * key2f(prefix[i]);
        }
        const float N = (float)n;
        out[0] = acc[0] / N;
        out[1] = (acc[1] + acc[2] + extra) / N;
    }
}

extern "C" void kernel_launch(void* const* d_in, const int* in_sizes, int n_in,
                              void* d_out, int out_size, void* d_ws, size_t ws_size,
                              hipStream_t stream) {
    const float* loc_t    = (const float*)d_in[0];
    const float* loc_data = (const float*)d_in[1];
    const int*   conf_t   = (const int*)d_in[2];
    const float* conf     = (const float*)d_in[3];
    float* out = (float*)d_out;

    char* ws = (char*)d_ws;
    const size_t off0 = (size_t)BB * PP * sizeof(float);   // 4 MB loss_c
    float*    loss_c    = (float*)ws;
    float*    acc       = (float*)(ws + off0);
    int*      num_pos   = (int*)(ws + off0 + 256);
    unsigned* prefix    = (unsigned*)(ws + off0 + 4608);
    unsigned* remaining = (unsigned*)(ws + off0 + 4864);
    unsigned* ghist     = (unsigned*)(ws + off0 + 5120);

    // zero acc/num_pos/prefix/remaining/ghist: 9472 words
    mbl_zero_kernel<<<37, 256, 0, stream>>>((unsigned*)(ws + off0), 9472);

    mbl_main_kernel<<<GRID_MAIN, TPB, 0, stream>>>(
        loc_t, loc_data, conf_t, conf, loss_c, acc, num_pos);

    const unsigned masks[4] = {0x00000000u, 0xFF000000u, 0xFFFF0000u, 0xFFFFFF00u};
    for (int p = 0; p < 4; ++p) {
        const int shift = 24 - 8 * p;
        mbl_hist_kernel<<<512, 256, 0, stream>>>(loss_c, prefix, ghist, shift, masks[p]);
        mbl_pick_kernel<<<BB, 256, 0, stream>>>(ghist, prefix, remaining, num_pos,
                                                shift, p == 0 ? 1 : 0);
    }
    mbl_sum_kernel<<<512, 256, 0, stream>>>(loss_c, prefix, acc);
    mbl_final_kernel<<<1, 64, 0, stream>>>(acc, num_pos, prefix, remaining, out);
}